// Round 7
// baseline (302.688 us; speedup 1.0000x reference)
//
#include <hip/hip_runtime.h>

// NonLocalBlock: B=2, C=256, N=D*H*W=6272, mid=128.
// R7 = R6 + K double-buffer + issue-early/write-late staging (T14):
//  - LDS: Ks0/Ks1 [64][136] + Vt [128][68] = 52224 B. QK on tile kt reads
//    the K staged during iter kt-1 -> starts right after the iter barrier.
//  - per iter: issue V[kt]+K[kt+1] global loads to regs FIRST, then
//    sched_barrier(0) to pin them (R4 failed because the compiler sank the
//    loads to their ds_write site; the fence is the fix, per rule #18),
//    then QK+softmax (~650cy) hide the ~300-500cy load latency, then
//    vmcnt+ds_write, barrier, PV, barrier. Same 2 barriers/tile as R6.
//  - unchanged from R6: q-split 4-wave QB=128, KS=4 flash-decode, in-reg P
//    (cvt_pkrtz + permlane32_swap), exp2 domain, defer-max, f16 Opart in
//    d_out, comb -> f16 attnW, f16 epi.
// ws: Qg f16 | Kg f16 | VtG f16 | attnW f16 | MLg f32 = 13.25 MB.

#define BB  2
#define CC  256
#define NN  6272
#define MID 128
#define KS  4
#define QB  128
#define NT  (NN / 64)
#define LOG2E 1.4426950408889634f

typedef _Float16 half2_t __attribute__((ext_vector_type(2)));
typedef _Float16 half4_t __attribute__((ext_vector_type(4)));
typedef _Float16 half8_t __attribute__((ext_vector_type(8)));
typedef float    floatx16 __attribute__((ext_vector_type(16)));
typedef int      i32x2 __attribute__((ext_vector_type(2)));
typedef unsigned u32x4 __attribute__((ext_vector_type(4)));

__device__ __forceinline__ void fma4(float4& a, const float4 v, const float s) {
    a.x += v.x * s; a.y += v.y * s; a.z += v.z * s; a.w += v.w * s;
}
__device__ __forceinline__ float dot4(const float4 a, const float4 b) {
    return a.x * b.x + a.y * b.y + a.z * b.z + a.w * b.w;
}
__device__ __forceinline__ unsigned pkrtz(float a, float b) {
    return __builtin_bit_cast(unsigned, __builtin_amdgcn_cvt_pkrtz(a, b));
}

// ---------------------------------------------------------------------------
// Projection: e_pj[n][m] = dot(w_pj[m,:], x[b,:,n]) + bias.
// pj 0 -> Qg f16 [b][n][128] (PRE-SCALED by log2e); pj 1 -> Kg f16 [b][n][128];
// pj 2 -> VtG f16 [b][128][n]. grid (NN/64, 3, BB), block 256.
// ---------------------------------------------------------------------------
__global__ __launch_bounds__(256, 2) void proj_kernel(
    const float* __restrict__ x,
    const float* __restrict__ w1, const float* __restrict__ bi1,
    const float* __restrict__ w2, const float* __restrict__ bi2,
    const float* __restrict__ w3, const float* __restrict__ bi3,
    _Float16* __restrict__ Qg, _Float16* __restrict__ Kg, _Float16* __restrict__ VtG)
{
    const int t  = threadIdx.x;
    const int n0 = blockIdx.x * 64;
    const int pj = blockIdx.y;
    const int b  = blockIdx.z;
    const float* w  = (pj == 0) ? w1 : (pj == 1) ? w2 : w3;
    const float* bi = (pj == 0) ? bi1 : (pj == 1) ? bi2 : bi3;
    const float qs  = (pj == 0) ? LOG2E : 1.0f;

    __shared__ float xs[CC * 68];
    {
        const float* xb = x + (size_t)b * CC * NN;
        for (int r = t; r < CC * 16; r += 256) {
            int c = r >> 4, j = (r & 15) << 2;
            float4 v = *(const float4*)(xb + (size_t)c * NN + n0 + j);
            *(float4*)&xs[c * 68 + j] = v;
        }
    }
    __syncthreads();

    const int n4 = (t & 15) << 2;   // 4 consecutive n per thread
    const int m0 = (t >> 4) << 3;   // 8 m-rows per thread
    float4 acc4[8];
    #pragma unroll
    for (int k = 0; k < 8; ++k) acc4[k] = make_float4(0.f, 0.f, 0.f, 0.f);

    for (int cc = 0; cc < CC; cc += 4) {
        float4 xv[4];
        #pragma unroll
        for (int u = 0; u < 4; ++u)
            xv[u] = *(const float4*)&xs[(cc + u) * 68 + n4];
        #pragma unroll
        for (int k = 0; k < 8; ++k) {
            float4 wq = *(const float4*)(w + (size_t)(m0 + k) * CC + cc);
            fma4(acc4[k], xv[0], wq.x);
            fma4(acc4[k], xv[1], wq.y);
            fma4(acc4[k], xv[2], wq.z);
            fma4(acc4[k], xv[3], wq.w);
        }
    }

    const float* af = (const float*)acc4;   // af[k*4 + i], i = n-sub, k = m-sub
    float bb[8];
    #pragma unroll
    for (int k = 0; k < 8; ++k) bb[k] = bi[m0 + k];

    if (pj < 2) {
        _Float16* eo = ((pj == 0) ? Qg : Kg) + (size_t)b * NN * MID;
        #pragma unroll
        for (int i = 0; i < 4; ++i) {
            half8_t h;
            #pragma unroll
            for (int k = 0; k < 8; ++k) h[k] = (_Float16)((af[k * 4 + i] + bb[k]) * qs);
            *(half8_t*)(eo + (size_t)(n0 + n4 + i) * MID + m0) = h;
        }
    } else {
        _Float16* eo = VtG + (size_t)b * MID * NN;
        #pragma unroll
        for (int k = 0; k < 8; ++k) {
            half4_t h;
            #pragma unroll
            for (int i = 0; i < 4; ++i) h[i] = (_Float16)(af[k * 4 + i] + bb[k]);
            *(half4_t*)(eo + (size_t)(m0 + k) * NN + n0 + n4) = h;
        }
    }
}

// ---------------------------------------------------------------------------
// Flash attention partial, f16 MFMA, q-split, in-reg P, K double-buffered.
// grid (NN/QB, KS, BB), block 256 (4 waves). Wave w owns q-rows [q0+w*32,+32).
// Iter kt: issue V[kt],K[kt+1] -> regs; sched_barrier; QK from KB[cur]
// (staged in iter kt-1); softmax (exp2 domain, in-reg pack); ds_write V,K;
// barrier; PV; barrier.
// S^T strip: col q = lane&31, row k' = (reg&3)+8*(reg>>2)+4*(lane>>5).
// LDS (52224 B): Ks0 [64][136] | Ks1 [64][136] | Vt [128][68].
// Osh [128][136] h aliases Ks0+Ks1 for the store transpose.
// ---------------------------------------------------------------------------
__global__ __launch_bounds__(256, 2) void attn_kernel(
    const _Float16* __restrict__ Qg, const _Float16* __restrict__ Kg,
    const _Float16* __restrict__ VtG, _Float16* __restrict__ Opart,
    float* __restrict__ MLg)
{
    const int t    = threadIdx.x;
    const int lane = t & 63;
    const int wave = t >> 6;        // q-strip owner (0..3)
    const int l31  = lane & 31;
    const int l5   = lane >> 5;
    const int q0   = blockIdx.x * QB;
    const int sp   = blockIdx.y;
    const int b    = blockIdx.z;
    const int kt0  = (NT * sp) / KS;
    const int kt1  = (NT * (sp + 1)) / KS;

    __shared__ __align__(16) char lds[52224];
    _Float16* Ks0 = (_Float16*)lds;               // 64*136 halfs
    _Float16* Ks1 = (_Float16*)(lds + 17408);     // 64*136 halfs
    _Float16* Vt  = (_Float16*)(lds + 34816);     // 128*68 halfs
    _Float16* Osh = (_Float16*)lds;               // [128][136] h alias (Ks0+Ks1)

    const _Float16* Qb = Qg + ((size_t)b * NN + q0 + wave * 32) * MID;
    const _Float16* Kb = Kg + (size_t)b * NN * MID;
    const _Float16* Vb = VtG + (size_t)b * MID * NN;

    // Q B-frags: loop-invariant, pinned in registers (wave's own 32 q-rows).
    half8_t qf[8];
    #pragma unroll
    for (int ds = 0; ds < 8; ++ds)
        qf[ds] = *(const half8_t*)(Qb + (size_t)l31 * MID + ds * 16 + l5 * 8);

    floatx16 o[4];
    #pragma unroll
    for (int dt = 0; dt < 4; ++dt)
        #pragma unroll
        for (int j = 0; j < 16; ++j) o[dt][j] = 0.f;
    float m_run = -3.0e38f, l_run = 0.f;   // m in log2 domain

    // Per-thread staging geometry (256 threads):
    //   K chunk it: row = it*16 + (t>>4), off = (t&15)*8
    //   V chunk it: d   = it*32 + (t>>3), off = (t&7)*8
    const int krow_t = t >> 4, koff_t = (t & 15) * 8;
    const int vd_t   = t >> 3, voff_t = (t & 7) * 8;

    // ---- prologue: stage K[kt0] into Ks0 ----
    #pragma unroll
    for (int it = 0; it < 4; ++it) {
        int r = it * 16 + krow_t;
        *(half8_t*)(Ks0 + r * 136 + koff_t) =
            *(const half8_t*)(Kb + (size_t)(kt0 * 64 + r) * MID + koff_t);
    }
    __syncthreads();

    for (int kt = kt0, cbuf = 0; kt < kt1; ++kt, cbuf ^= 1) {
        const int nk = kt * 64;
        _Float16* KBcur = cbuf ? Ks1 : Ks0;
        _Float16* KBnxt = cbuf ? Ks0 : Ks1;

        // ---- issue V[kt] and K[kt+1] global loads -> regs (EARLY) ----
        const int nk2 = (kt + 1 < kt1) ? nk + 64 : nk;   // tail: harmless reload
        half8_t vreg[4], kreg[4];
        #pragma unroll
        for (int it = 0; it < 4; ++it)
            vreg[it] = *(const half8_t*)(Vb + (size_t)(it * 32 + vd_t) * NN + nk + voff_t);
        #pragma unroll
        for (int it = 0; it < 4; ++it)
            kreg[it] = *(const half8_t*)(Kb + (size_t)(nk2 + it * 16 + krow_t) * MID + koff_t);
        __builtin_amdgcn_sched_barrier(0);   // pin the loads above this point

        // ---- S^T strips from KBcur (staged last iter): s0, s1 ----
        floatx16 s0, s1;
        #pragma unroll
        for (int j = 0; j < 16; ++j) { s0[j] = 0.f; s1[j] = 0.f; }
        const _Float16* krow0 = KBcur + l31 * 136 + l5 * 8;
        const _Float16* krow1 = KBcur + (32 + l31) * 136 + l5 * 8;
        #pragma unroll
        for (int ds = 0; ds < 8; ++ds) {
            s0 = __builtin_amdgcn_mfma_f32_32x32x16_f16(
                     *(const half8_t*)(krow0 + ds * 16), qf[ds], s0, 0, 0, 0);
            s1 = __builtin_amdgcn_mfma_f32_32x32x16_f16(
                     *(const half8_t*)(krow1 + ds * 16), qf[ds], s1, 0, 0, 0);
        }

        // ---- online softmax over 64 k' (lane: one q col, 32 of 64 rows) ----
        float tmax = fmaxf(s0[0], s1[0]);
        #pragma unroll
        for (int j = 1; j < 16; ++j) tmax = fmaxf(tmax, fmaxf(s0[j], s1[j]));
        tmax = fmaxf(tmax, __shfl_xor(tmax, 32));

        // defer-max (THR=0): skip rescale when no lane's max grew (exact).
        if (!__all(tmax <= m_run)) {
            const float m_new = fmaxf(m_run, tmax);
            const float alpha = exp2f(m_run - m_new);
            m_run = m_new;
            l_run *= alpha;
            #pragma unroll
            for (int dt = 0; dt < 4; ++dt)
                #pragma unroll
                for (int j = 0; j < 16; ++j) o[dt][j] *= alpha;
        }

        // ---- P in registers: u0[G] = k' 8G+4*l5+{0,1}, u1[G] = +{2,3} ----
        float psum = 0.f;
        unsigned u0[8], u1[8];
        #pragma unroll
        for (int g = 0; g < 4; ++g) {
            float p0 = exp2f(s0[4 * g + 0] - m_run);
            float p1 = exp2f(s0[4 * g + 1] - m_run);
            float p2 = exp2f(s0[4 * g + 2] - m_run);
            float p3 = exp2f(s0[4 * g + 3] - m_run);
            psum += (p0 + p1) + (p2 + p3);
            u0[g] = pkrtz(p0, p1);
            u1[g] = pkrtz(p2, p3);
        }
        #pragma unroll
        for (int g = 0; g < 4; ++g) {
            float p0 = exp2f(s1[4 * g + 0] - m_run);
            float p1 = exp2f(s1[4 * g + 1] - m_run);
            float p2 = exp2f(s1[4 * g + 2] - m_run);
            float p3 = exp2f(s1[4 * g + 3] - m_run);
            psum += (p0 + p1) + (p2 + p3);
            u0[4 + g] = pkrtz(p0, p1);
            u1[4 + g] = pkrtz(p2, p3);
        }
        psum += __shfl_xor(psum, 32);
        l_run += psum;

        // ---- write-late: V[kt] -> Vt, K[kt+1] -> KBnxt (loads have drained) ----
        #pragma unroll
        for (int it = 0; it < 4; ++it)
            *(half8_t*)(Vt + (it * 32 + vd_t) * 68 + voff_t) = vreg[it];
        #pragma unroll
        for (int it = 0; it < 4; ++it)
            *(half8_t*)(KBnxt + (it * 16 + krow_t) * 136 + koff_t) = kreg[it];
        __syncthreads();   // V[kt] visible (and K[kt+1] staged)

        // ---- O^T += V^T . P^T, K = 64; B-frags built via permlane32_swap ----
        #pragma unroll
        for (int ks = 0; ks < 4; ++ks) {
            i32x2 rA = __builtin_amdgcn_permlane32_swap(
                           (int)u0[2 * ks], (int)u0[2 * ks + 1], false, false);
            i32x2 rB = __builtin_amdgcn_permlane32_swap(
                           (int)u1[2 * ks], (int)u1[2 * ks + 1], false, false);
            u32x4 pw;
            pw[0] = (unsigned)rA[0]; pw[1] = (unsigned)rB[0];
            pw[2] = (unsigned)rA[1]; pw[3] = (unsigned)rB[1];
            half8_t pf = __builtin_bit_cast(half8_t, pw);
            const _Float16* vcol = Vt + ks * 16 + l5 * 8;
            #pragma unroll
            for (int dt = 0; dt < 4; ++dt)
                o[dt] = __builtin_amdgcn_mfma_f32_32x32x16_f16(
                            *(const half8_t*)(vcol + (dt * 32 + l31) * 68), pf,
                            o[dt], 0, 0, 0);
        }
        __syncthreads();   // end-of-iter: PV reads done before next V/K writes
    }

    // ---- per-row (m,l) out; transpose O via LDS; store UNNORMALIZED f16 ----
    if (l5 == 0) {
        float* mlb = MLg + ((size_t)(b * KS + sp) * 2) * NN;
        mlb[q0 + wave * 32 + l31]      = m_run;   // log2-domain max
        mlb[NN + q0 + wave * 32 + l31] = l_run;
    }

    // Osh aliases Ks0+Ks1: all waves past the loop-end barrier.
    #pragma unroll
    for (int dt = 0; dt < 4; ++dt)
        #pragma unroll
        for (int h = 0; h < 4; ++h) {
            half4_t v;
            #pragma unroll
            for (int i = 0; i < 4; ++i) v[i] = (_Float16)o[dt][4 * h + i];
            // d = dt*32 + 8h + 4*l5 + i
            *(half4_t*)(Osh + (wave * 32 + l31) * 136 + dt * 32 + 8 * h + 4 * l5) = v;
        }
    __syncthreads();
    _Float16* Ob = Opart + ((size_t)(b * KS + sp) * NN + q0) * MID;
    #pragma unroll
    for (int it = 0; it < 8; ++it) {
        int c = it * 256 + t;           // 2048 half8-chunks: 128 q-rows x 16
        int q = c >> 4, g = c & 15;
        *(half8_t*)(Ob + (size_t)q * MID + g * 8) =
            *(const half8_t*)(Osh + q * 136 + g * 8);
    }
}

// ---------------------------------------------------------------------------
// Combine the KS partials: attnW = sum_s O_s*2^(m_s-m) / sum_s l_s*2^(m_s-m).
// Opart f16 lives in d_out; result written as f16 to ws attnW.
// grid (NN/32, BB), block 256: thread owns (q, 16 d-cols).
// ---------------------------------------------------------------------------
__global__ __launch_bounds__(256, 4) void comb_kernel(
    const _Float16* __restrict__ Opart, const float* __restrict__ MLg,
    _Float16* __restrict__ attnW)
{
    const int t  = threadIdx.x;
    const int b  = blockIdx.y;
    const int q  = blockIdx.x * 32 + (t >> 3);
    const int dg = (t & 7) * 16;

    float mv[KS], lv[KS];
    float m_g = -3.0e38f;
    #pragma unroll
    for (int s = 0; s < KS; ++s) {
        const float* mlb = MLg + ((size_t)(b * KS + s) * 2) * NN;
        mv[s] = mlb[q];
        lv[s] = mlb[NN + q];
        m_g = fmaxf(m_g, mv[s]);
    }
    float lg = 0.f, w[KS];
    #pragma unroll
    for (int s = 0; s < KS; ++s) { w[s] = exp2f(mv[s] - m_g); lg += lv[s] * w[s]; }
    const float inv = 1.0f / lg;

    float acc[16];
    #pragma unroll
    for (int j = 0; j < 16; ++j) acc[j] = 0.f;
    #pragma unroll
    for (int s = 0; s < KS; ++s) {
        const half8_t* Op = (const half8_t*)(Opart + ((size_t)(b * KS + s) * NN + q) * MID + dg);
        half8_t v0 = Op[0], v1 = Op[1];
        #pragma unroll
        for (int j = 0; j < 8; ++j) {
            acc[j]     += (float)v0[j] * w[s];
            acc[8 + j] += (float)v1[j] * w[s];
        }
    }
    half8_t h0, h1;
    #pragma unroll
    for (int j = 0; j < 8; ++j) {
        h0[j] = (_Float16)(acc[j] * inv);
        h1[j] = (_Float16)(acc[8 + j] * inv);
    }
    half8_t* Ow = (half8_t*)(attnW + ((size_t)b * NN + q) * MID + dg);
    Ow[0] = h0; Ow[1] = h1;
}

// ---------------------------------------------------------------------------
// Epilogue: out[b][c][n] = x + w4 @ attn^T + b4. grid (NN/64, BB), block 256.
// attnW is f16 [b][n][128]; converted to f32 while staging to LDS.
// ---------------------------------------------------------------------------
__global__ __launch_bounds__(256, 2) void epi_kernel(
    const _Float16* __restrict__ attnW, const float* __restrict__ w4,
    const float* __restrict__ b4, const float* __restrict__ x,
    float* __restrict__ out)
{
    const int t  = threadIdx.x;
    const int n0 = blockIdx.x * 64;
    const int b  = blockIdx.y;

    __shared__ float as[64 * 132];
    for (int r = t; r < 64 * 16; r += 256) {
        int q = r >> 4, g = r & 15;
        half8_t v = *(const half8_t*)(attnW + ((size_t)b * NN + n0 + q) * MID + g * 8);
        float* dst = &as[q * 132 + g * 8];
        #pragma unroll
        for (int j = 0; j < 8; ++j) dst[j] = (float)v[j];
    }
    __syncthreads();

    const int n4 = (t & 15) << 2;
    const int c0 = (t >> 4) << 4;
    float4 accE[16];
    #pragma unroll
    for (int k = 0; k < 16; ++k) accE[k] = make_float4(0.f, 0.f, 0.f, 0.f);

    for (int ms = 0; ms < 32; ++ms) {
        float4 av[4];
        #pragma unroll
        for (int i = 0; i < 4; ++i)
            av[i] = *(const float4*)&as[(n4 + i) * 132 + (ms << 2)];
        #pragma unroll
        for (int k = 0; k < 16; ++k) {
            float4 wq = *(const float4*)(w4 + (size_t)(c0 + k) * MID + (ms << 2));
            accE[k].x += dot4(av[0], wq);
            accE[k].y += dot4(av[1], wq);
            accE[k].z += dot4(av[2], wq);
            accE[k].w += dot4(av[3], wq);
        }
    }

    #pragma unroll
    for (int k = 0; k < 16; ++k) {
        const int c = c0 + k;
        const float bv = b4[c];
        const size_t off = ((size_t)b * CC + c) * NN + n0 + n4;
        float4 xr = *(const float4*)(x + off);
        float4 r;
        r.x = accE[k].x + bv + xr.x;
        r.y = accE[k].y + bv + xr.y;
        r.z = accE[k].z + bv + xr.z;
        r.w = accE[k].w + bv + xr.w;
        *(float4*)(out + off) = r;
    }
}

extern "C" void kernel_launch(void* const* d_in, const int* in_sizes, int n_in,
                              void* d_out, int out_size, void* d_ws, size_t ws_size,
                              hipStream_t stream)
{
    const float* x  = (const float*)d_in[0];
    const float* w1 = (const float*)d_in[1];
    const float* b1 = (const float*)d_in[2];
    const float* w2 = (const float*)d_in[3];
    const float* b2 = (const float*)d_in[4];
    const float* w3 = (const float*)d_in[5];
    const float* b3 = (const float*)d_in[6];
    const float* w4 = (const float*)d_in[7];
    const float* b4 = (const float*)d_in[8];
    float* out = (float*)d_out;

    // ws: Qg f16 [B][N][128] | Kg f16 [B][N][128] | VtG f16 [B][128][N]
    //   | attnW f16 [B][N][128] | MLg f32 [B][KS][2][N]   (13.25 MB total)
    // Opart f16 [B][KS][N][128] aliases d_out (KS=4: exactly out_size).
    _Float16* Qg    = (_Float16*)d_ws;
    _Float16* Kg    = Qg + (size_t)BB * NN * MID;
    _Float16* VtG   = Kg + (size_t)BB * NN * MID;
    _Float16* attnW = VtG + (size_t)BB * NN * MID;
    float* MLg      = (float*)(attnW + (size_t)BB * NN * MID);
    _Float16* Opart = (_Float16*)d_out;

    proj_kernel<<<dim3(NN / 64, 3, BB), 256, 0, stream>>>(x, w1, b1, w2, b2, w3, b3, Qg, Kg, VtG);
    attn_kernel<<<dim3(NN / QB, KS, BB), 256, 0, stream>>>(Qg, Kg, VtG, Opart, MLg);
    comb_kernel<<<dim3(NN / 32, BB), 256, 0, stream>>>(Opart, MLg, attnW);
    epi_kernel<<<dim3(NN / 64, BB), 256, 0, stream>>>(attnW, w4, b4, x, out);
}

// Round 8
// 288.841 us; speedup vs baseline: 1.0479x; 1.0479x over previous
//
#include <hip/hip_runtime.h>

// NonLocalBlock: B=2, C=256, N=D*H*W=6272, mid=128.
// R8 = R7 attn/comb (unchanged) + MFMA proj + MFMA epi:
//  - proj: f16 MFMA GEMM with SPLIT x (xhi + xlo both staged; x exact to
//    2^-22 -- only w's f16 rounding remains, ~3e-4 on e, smaller than the
//    existing f16 output rounding). 2 c-phases of [64][140] hi/lo tiles
//    (35.8 KB LDS); 4 waves x 6 tiles (3proj x 4mt x 2nt); w cvt'd f16
//    in-flight via cvt_pkrtz. Q/K: D[n][m] (A=x,B=w); V: D[m][n] (A=w,B=x).
//  - epi: no-LDS MFMA: A=w4 (cvt in-flight), B=attnW f16 rows (already f16
//    in the passing pipeline), D[c][n] + f32 bias + f32 x residual -> out.
//  - attn (R7: q-split 4-wave, KS=4, in-reg P, K-dbuf) and comb unchanged.
// ws: Qg f16 | Kg f16 | VtG f16 | attnW f16 | MLg f32 = 13.25 MB.

#define BB  2
#define CC  256
#define NN  6272
#define MID 128
#define KS  4
#define QB  128
#define NT  (NN / 64)
#define LOG2E 1.4426950408889634f

typedef _Float16 half2_t __attribute__((ext_vector_type(2)));
typedef _Float16 half4_t __attribute__((ext_vector_type(4)));
typedef _Float16 half8_t __attribute__((ext_vector_type(8)));
typedef float    floatx16 __attribute__((ext_vector_type(16)));
typedef int      i32x2 __attribute__((ext_vector_type(2)));
typedef unsigned u32x4 __attribute__((ext_vector_type(4)));

__device__ __forceinline__ unsigned pkrtz(float a, float b) {
    return __builtin_bit_cast(unsigned, __builtin_amdgcn_cvt_pkrtz(a, b));
}
// Convert 8 consecutive f32 (two float4) to a half8 via cvt_pkrtz.
__device__ __forceinline__ half8_t cvt8(const float* p) {
    float4 f0 = *(const float4*)p;
    float4 f1 = *(const float4*)(p + 4);
    u32x4 u;
    u[0] = pkrtz(f0.x, f0.y); u[1] = pkrtz(f0.z, f0.w);
    u[2] = pkrtz(f1.x, f1.y); u[3] = pkrtz(f1.z, f1.w);
    return __builtin_bit_cast(half8_t, u);
}

// ---------------------------------------------------------------------------
// Projection (f16 MFMA, split-x): e_pj[n][m] = dot(w_pj[m,:], x[b,:,n]) + bias.
// pj 0 -> Qg f16 [b][n][128] (PRE-SCALED by log2e); pj 1 -> Kg f16 [b][n][128];
// pj 2 -> VtG f16 [b][128][n]. grid (NN/64, BB), block 256 (4 waves).
// Block: 64 n x 128 m x 3 proj. Wave owns 6 D-tiles (tau = wave*6+i:
// pj=tau>>3, mt=(tau>>1)&3, nt=tau&1), accumulating over 2 c-phases.
// x staged TRANSPOSED+SPLIT: xhi/xlo [64][140] f16 (hi=f16(x), lo=f16(x-hi)).
// Fragment layouts (from verified attn kernel): A lane->row, B lane->col,
// D col = l31(B), row = (j&3)+8*(j>>2)+4*l5.
// ---------------------------------------------------------------------------
__global__ __launch_bounds__(256, 2) void proj_kernel(
    const float* __restrict__ x,
    const float* __restrict__ w1, const float* __restrict__ bi1,
    const float* __restrict__ w2, const float* __restrict__ bi2,
    const float* __restrict__ w3, const float* __restrict__ bi3,
    _Float16* __restrict__ Qg, _Float16* __restrict__ Kg, _Float16* __restrict__ VtG)
{
    const int t    = threadIdx.x;
    const int lane = t & 63;
    const int wave = t >> 6;
    const int l31  = lane & 31;
    const int l5   = lane >> 5;
    const int n0   = blockIdx.x * 64;
    const int b    = blockIdx.y;

    __shared__ _Float16 xhi[64 * 140];   // [n][c-local], stride 140 (2-way free)
    __shared__ _Float16 xlo[64 * 140];

    floatx16 acc[6];
    #pragma unroll
    for (int i = 0; i < 6; ++i)
        #pragma unroll
        for (int j = 0; j < 16; ++j) acc[i][j] = 0.f;

    for (int phase = 0; phase < 2; ++phase) {
        const int cb = phase * 128;
        if (phase) __syncthreads();   // all phase-0 reads done before restage
        // ---- stage x[cb..cb+128][n0..n0+64] transposed + hi/lo split ----
        for (int it = 0; it < 8; ++it) {
            int r = it * 256 + t;
            int c = r >> 4, j4 = (r & 15) << 2;
            float4 v = *(const float4*)(x + ((size_t)b * CC + cb + c) * NN + n0 + j4);
            float vv[4] = {v.x, v.y, v.z, v.w};
            #pragma unroll
            for (int i = 0; i < 4; ++i) {
                _Float16 h = (_Float16)vv[i];
                xhi[(j4 + i) * 140 + c] = h;
                xlo[(j4 + i) * 140 + c] = (_Float16)(vv[i] - (float)h);
            }
        }
        __syncthreads();

        // ---- accumulate this phase's 8 k-steps into all 6 tiles ----
        #pragma unroll
        for (int i = 0; i < 6; ++i) {
            const int tau = wave * 6 + i;
            const int pj = tau >> 3, mt = (tau >> 1) & 3, nt = tau & 1;
            const float* w = (pj == 0) ? w1 : (pj == 1) ? w2 : w3;
            const float* wrow = w + (size_t)(mt * 32 + l31) * CC + cb + l5 * 8;
            const _Float16* xr_hi = xhi + (nt * 32 + l31) * 140 + l5 * 8;
            const _Float16* xr_lo = xlo + (nt * 32 + l31) * 140 + l5 * 8;
            #pragma unroll
            for (int ds = 0; ds < 8; ++ds) {
                half8_t wf = cvt8(wrow + ds * 16);
                half8_t ah = *(const half8_t*)(xr_hi + ds * 16);
                half8_t al = *(const half8_t*)(xr_lo + ds * 16);
                if (pj < 2) {   // D[n][m]: A = x (rows n), B = w (cols m)
                    acc[i] = __builtin_amdgcn_mfma_f32_32x32x16_f16(ah, wf, acc[i], 0, 0, 0);
                    acc[i] = __builtin_amdgcn_mfma_f32_32x32x16_f16(al, wf, acc[i], 0, 0, 0);
                } else {        // D[m][n]: A = w (rows m), B = x (cols n)
                    acc[i] = __builtin_amdgcn_mfma_f32_32x32x16_f16(wf, ah, acc[i], 0, 0, 0);
                    acc[i] = __builtin_amdgcn_mfma_f32_32x32x16_f16(wf, al, acc[i], 0, 0, 0);
                }
            }
        }
    }

    // ---- stores ----
    #pragma unroll
    for (int i = 0; i < 6; ++i) {
        const int tau = wave * 6 + i;
        const int pj = tau >> 3, mt = (tau >> 1) & 3, nt = tau & 1;
        if (pj < 2) {
            // D[n][m]: lane col m = mt*32+l31; rows n
            const float bm = ((pj == 0) ? bi1 : bi2)[mt * 32 + l31];
            const float sc = (pj == 0) ? LOG2E : 1.0f;
            _Float16* eo = ((pj == 0) ? Qg : Kg) + (size_t)b * NN * MID;
            #pragma unroll
            for (int j = 0; j < 16; ++j) {
                int n = n0 + nt * 32 + (j & 3) + 8 * (j >> 2) + 4 * l5;
                eo[(size_t)n * MID + mt * 32 + l31] = (_Float16)((acc[i][j] + bm) * sc);
            }
        } else {
            // D[m][n]: lane col n; rows m
            _Float16* eo = VtG + (size_t)b * MID * NN;
            #pragma unroll
            for (int j = 0; j < 16; ++j) {
                int m = mt * 32 + (j & 3) + 8 * (j >> 2) + 4 * l5;
                eo[(size_t)m * NN + n0 + nt * 32 + l31] = (_Float16)(acc[i][j] + bi3[m]);
            }
        }
    }
}

// ---------------------------------------------------------------------------
// Flash attention partial (UNCHANGED R7), f16 MFMA, q-split, in-reg P,
// K double-buffered. grid (NN/QB, KS, BB), block 256 (4 waves).
// LDS (52224 B): Ks0 [64][136] | Ks1 [64][136] | Vt [128][68].
// ---------------------------------------------------------------------------
__global__ __launch_bounds__(256, 2) void attn_kernel(
    const _Float16* __restrict__ Qg, const _Float16* __restrict__ Kg,
    const _Float16* __restrict__ VtG, _Float16* __restrict__ Opart,
    float* __restrict__ MLg)
{
    const int t    = threadIdx.x;
    const int lane = t & 63;
    const int wave = t >> 6;        // q-strip owner (0..3)
    const int l31  = lane & 31;
    const int l5   = lane >> 5;
    const int q0   = blockIdx.x * QB;
    const int sp   = blockIdx.y;
    const int b    = blockIdx.z;
    const int kt0  = (NT * sp) / KS;
    const int kt1  = (NT * (sp + 1)) / KS;

    __shared__ __align__(16) char lds[52224];
    _Float16* Ks0 = (_Float16*)lds;               // 64*136 halfs
    _Float16* Ks1 = (_Float16*)(lds + 17408);     // 64*136 halfs
    _Float16* Vt  = (_Float16*)(lds + 34816);     // 128*68 halfs
    _Float16* Osh = (_Float16*)lds;               // [128][136] h alias (Ks0+Ks1)

    const _Float16* Qb = Qg + ((size_t)b * NN + q0 + wave * 32) * MID;
    const _Float16* Kb = Kg + (size_t)b * NN * MID;
    const _Float16* Vb = VtG + (size_t)b * MID * NN;

    half8_t qf[8];
    #pragma unroll
    for (int ds = 0; ds < 8; ++ds)
        qf[ds] = *(const half8_t*)(Qb + (size_t)l31 * MID + ds * 16 + l5 * 8);

    floatx16 o[4];
    #pragma unroll
    for (int dt = 0; dt < 4; ++dt)
        #pragma unroll
        for (int j = 0; j < 16; ++j) o[dt][j] = 0.f;
    float m_run = -3.0e38f, l_run = 0.f;   // m in log2 domain

    const int krow_t = t >> 4, koff_t = (t & 15) * 8;
    const int vd_t   = t >> 3, voff_t = (t & 7) * 8;

    #pragma unroll
    for (int it = 0; it < 4; ++it) {
        int r = it * 16 + krow_t;
        *(half8_t*)(Ks0 + r * 136 + koff_t) =
            *(const half8_t*)(Kb + (size_t)(kt0 * 64 + r) * MID + koff_t);
    }
    __syncthreads();

    for (int kt = kt0, cbuf = 0; kt < kt1; ++kt, cbuf ^= 1) {
        const int nk = kt * 64;
        _Float16* KBcur = cbuf ? Ks1 : Ks0;
        _Float16* KBnxt = cbuf ? Ks0 : Ks1;

        const int nk2 = (kt + 1 < kt1) ? nk + 64 : nk;
        half8_t vreg[4], kreg[4];
        #pragma unroll
        for (int it = 0; it < 4; ++it)
            vreg[it] = *(const half8_t*)(Vb + (size_t)(it * 32 + vd_t) * NN + nk + voff_t);
        #pragma unroll
        for (int it = 0; it < 4; ++it)
            kreg[it] = *(const half8_t*)(Kb + (size_t)(nk2 + it * 16 + krow_t) * MID + koff_t);
        __builtin_amdgcn_sched_barrier(0);

        floatx16 s0, s1;
        #pragma unroll
        for (int j = 0; j < 16; ++j) { s0[j] = 0.f; s1[j] = 0.f; }
        const _Float16* krow0 = KBcur + l31 * 136 + l5 * 8;
        const _Float16* krow1 = KBcur + (32 + l31) * 136 + l5 * 8;
        #pragma unroll
        for (int ds = 0; ds < 8; ++ds) {
            s0 = __builtin_amdgcn_mfma_f32_32x32x16_f16(
                     *(const half8_t*)(krow0 + ds * 16), qf[ds], s0, 0, 0, 0);
            s1 = __builtin_amdgcn_mfma_f32_32x32x16_f16(
                     *(const half8_t*)(krow1 + ds * 16), qf[ds], s1, 0, 0, 0);
        }

        float tmax = fmaxf(s0[0], s1[0]);
        #pragma unroll
        for (int j = 1; j < 16; ++j) tmax = fmaxf(tmax, fmaxf(s0[j], s1[j]));
        tmax = fmaxf(tmax, __shfl_xor(tmax, 32));

        if (!__all(tmax <= m_run)) {
            const float m_new = fmaxf(m_run, tmax);
            const float alpha = exp2f(m_run - m_new);
            m_run = m_new;
            l_run *= alpha;
            #pragma unroll
            for (int dt = 0; dt < 4; ++dt)
                #pragma unroll
                for (int j = 0; j < 16; ++j) o[dt][j] *= alpha;
        }

        float psum = 0.f;
        unsigned u0[8], u1[8];
        #pragma unroll
        for (int g = 0; g < 4; ++g) {
            float p0 = exp2f(s0[4 * g + 0] - m_run);
            float p1 = exp2f(s0[4 * g + 1] - m_run);
            float p2 = exp2f(s0[4 * g + 2] - m_run);
            float p3 = exp2f(s0[4 * g + 3] - m_run);
            psum += (p0 + p1) + (p2 + p3);
            u0[g] = pkrtz(p0, p1);
            u1[g] = pkrtz(p2, p3);
        }
        #pragma unroll
        for (int g = 0; g < 4; ++g) {
            float p0 = exp2f(s1[4 * g + 0] - m_run);
            float p1 = exp2f(s1[4 * g + 1] - m_run);
            float p2 = exp2f(s1[4 * g + 2] - m_run);
            float p3 = exp2f(s1[4 * g + 3] - m_run);
            psum += (p0 + p1) + (p2 + p3);
            u0[4 + g] = pkrtz(p0, p1);
            u1[4 + g] = pkrtz(p2, p3);
        }
        psum += __shfl_xor(psum, 32);
        l_run += psum;

        #pragma unroll
        for (int it = 0; it < 4; ++it)
            *(half8_t*)(Vt + (it * 32 + vd_t) * 68 + voff_t) = vreg[it];
        #pragma unroll
        for (int it = 0; it < 4; ++it)
            *(half8_t*)(KBnxt + (it * 16 + krow_t) * 136 + koff_t) = kreg[it];
        __syncthreads();

        #pragma unroll
        for (int ks = 0; ks < 4; ++ks) {
            i32x2 rA = __builtin_amdgcn_permlane32_swap(
                           (int)u0[2 * ks], (int)u0[2 * ks + 1], false, false);
            i32x2 rB = __builtin_amdgcn_permlane32_swap(
                           (int)u1[2 * ks], (int)u1[2 * ks + 1], false, false);
            u32x4 pw;
            pw[0] = (unsigned)rA[0]; pw[1] = (unsigned)rB[0];
            pw[2] = (unsigned)rA[1]; pw[3] = (unsigned)rB[1];
            half8_t pf = __builtin_bit_cast(half8_t, pw);
            const _Float16* vcol = Vt + ks * 16 + l5 * 8;
            #pragma unroll
            for (int dt = 0; dt < 4; ++dt)
                o[dt] = __builtin_amdgcn_mfma_f32_32x32x16_f16(
                            *(const half8_t*)(vcol + (dt * 32 + l31) * 68), pf,
                            o[dt], 0, 0, 0);
        }
        __syncthreads();
    }

    if (l5 == 0) {
        float* mlb = MLg + ((size_t)(b * KS + sp) * 2) * NN;
        mlb[q0 + wave * 32 + l31]      = m_run;
        mlb[NN + q0 + wave * 32 + l31] = l_run;
    }

    #pragma unroll
    for (int dt = 0; dt < 4; ++dt)
        #pragma unroll
        for (int h = 0; h < 4; ++h) {
            half4_t v;
            #pragma unroll
            for (int i = 0; i < 4; ++i) v[i] = (_Float16)o[dt][4 * h + i];
            *(half4_t*)(Osh + (wave * 32 + l31) * 136 + dt * 32 + 8 * h + 4 * l5) = v;
        }
    __syncthreads();
    _Float16* Ob = Opart + ((size_t)(b * KS + sp) * NN + q0) * MID;
    #pragma unroll
    for (int it = 0; it < 8; ++it) {
        int c = it * 256 + t;
        int q = c >> 4, g = c & 15;
        *(half8_t*)(Ob + (size_t)q * MID + g * 8) =
            *(const half8_t*)(Osh + q * 136 + g * 8);
    }
}

// ---------------------------------------------------------------------------
// Combine the KS partials (UNCHANGED): attnW = sum O_s*2^(m_s-m) / sum l_s*2^(m_s-m).
// grid (NN/32, BB), block 256.
// ---------------------------------------------------------------------------
__global__ __launch_bounds__(256, 4) void comb_kernel(
    const _Float16* __restrict__ Opart, const float* __restrict__ MLg,
    _Float16* __restrict__ attnW)
{
    const int t  = threadIdx.x;
    const int b  = blockIdx.y;
    const int q  = blockIdx.x * 32 + (t >> 3);
    const int dg = (t & 7) * 16;

    float mv[KS], lv[KS];
    float m_g = -3.0e38f;
    #pragma unroll
    for (int s = 0; s < KS; ++s) {
        const float* mlb = MLg + ((size_t)(b * KS + s) * 2) * NN;
        mv[s] = mlb[q];
        lv[s] = mlb[NN + q];
        m_g = fmaxf(m_g, mv[s]);
    }
    float lg = 0.f, w[KS];
    #pragma unroll
    for (int s = 0; s < KS; ++s) { w[s] = exp2f(mv[s] - m_g); lg += lv[s] * w[s]; }
    const float inv = 1.0f / lg;

    float acc[16];
    #pragma unroll
    for (int j = 0; j < 16; ++j) acc[j] = 0.f;
    #pragma unroll
    for (int s = 0; s < KS; ++s) {
        const half8_t* Op = (const half8_t*)(Opart + ((size_t)(b * KS + s) * NN + q) * MID + dg);
        half8_t v0 = Op[0], v1 = Op[1];
        #pragma unroll
        for (int j = 0; j < 8; ++j) {
            acc[j]     += (float)v0[j] * w[s];
            acc[8 + j] += (float)v1[j] * w[s];
        }
    }
    half8_t h0, h1;
    #pragma unroll
    for (int j = 0; j < 8; ++j) {
        h0[j] = (_Float16)(acc[j] * inv);
        h1[j] = (_Float16)(acc[8 + j] * inv);
    }
    half8_t* Ow = (half8_t*)(attnW + ((size_t)b * NN + q) * MID + dg);
    Ow[0] = h0; Ow[1] = h1;
}

// ---------------------------------------------------------------------------
// Epilogue (f16 MFMA, no LDS): out[b][c][n] = x + w4 @ attn^T + b4.
// grid (NN/64, BB), block 256 (4 waves). 16 D-tiles (8 c x 2 n), 4 per wave.
// A = w4 rows c (cvt f32->f16 in flight); B = attnW rows n (already f16);
// D[c][n] + f32 bias + f32 x residual -> f32 out (128B coalesced runs).
// ---------------------------------------------------------------------------
__global__ __launch_bounds__(256, 2) void epi_kernel(
    const _Float16* __restrict__ attnW, const float* __restrict__ w4,
    const float* __restrict__ b4, const float* __restrict__ x,
    float* __restrict__ out)
{
    const int t    = threadIdx.x;
    const int lane = t & 63;
    const int wave = t >> 6;
    const int l31  = lane & 31;
    const int l5   = lane >> 5;
    const int n0   = blockIdx.x * 64;
    const int b    = blockIdx.y;

    #pragma unroll
    for (int i = 0; i < 4; ++i) {
        const int tau = wave * 4 + i;
        const int ct = tau >> 1, nt = tau & 1;
        floatx16 acc;
        #pragma unroll
        for (int j = 0; j < 16; ++j) acc[j] = 0.f;

        const float* wrow = w4 + (size_t)(ct * 32 + l31) * MID + l5 * 8;
        const _Float16* brow = attnW + ((size_t)b * NN + n0 + nt * 32 + l31) * MID + l5 * 8;
        #pragma unroll
        for (int ds = 0; ds < 8; ++ds) {
            half8_t wf = cvt8(wrow + ds * 16);
            half8_t bf = *(const half8_t*)(brow + ds * 16);
            acc = __builtin_amdgcn_mfma_f32_32x32x16_f16(wf, bf, acc, 0, 0, 0);
        }
        // D[c][n]: lane col n = n0+nt*32+l31; rows c = ct*32 + rowof(j)
        #pragma unroll
        for (int j = 0; j < 16; ++j) {
            int c = ct * 32 + (j & 3) + 8 * (j >> 2) + 4 * l5;
            size_t off = ((size_t)b * CC + c) * NN + n0 + nt * 32 + l31;
            out[off] = acc[j] + b4[c] + x[off];
        }
    }
}

extern "C" void kernel_launch(void* const* d_in, const int* in_sizes, int n_in,
                              void* d_out, int out_size, void* d_ws, size_t ws_size,
                              hipStream_t stream)
{
    const float* x  = (const float*)d_in[0];
    const float* w1 = (const float*)d_in[1];
    const float* b1 = (const float*)d_in[2];
    const float* w2 = (const float*)d_in[3];
    const float* b2 = (const float*)d_in[4];
    const float* w3 = (const float*)d_in[5];
    const float* b3 = (const float*)d_in[6];
    const float* w4 = (const float*)d_in[7];
    const float* b4 = (const float*)d_in[8];
    float* out = (float*)d_out;

    // ws: Qg f16 [B][N][128] | Kg f16 [B][N][128] | VtG f16 [B][128][N]
    //   | attnW f16 [B][N][128] | MLg f32 [B][KS][2][N]   (13.25 MB total)
    // Opart f16 [B][KS][N][128] aliases d_out (KS=4: exactly out_size).
    _Float16* Qg    = (_Float16*)d_ws;
    _Float16* Kg    = Qg + (size_t)BB * NN * MID;
    _Float16* VtG   = Kg + (size_t)BB * NN * MID;
    _Float16* attnW = VtG + (size_t)BB * NN * MID;
    float* MLg      = (float*)(attnW + (size_t)BB * NN * MID);
    _Float16* Opart = (_Float16*)d_out;

    proj_kernel<<<dim3(NN / 64, BB), 256, 0, stream>>>(x, w1, b1, w2, b2, w3, b3, Qg, Kg, VtG);
    attn_kernel<<<dim3(NN / QB, KS, BB), 256, 0, stream>>>(Qg, Kg, VtG, Opart, MLg);
    comb_kernel<<<dim3(NN / 32, BB), 256, 0, stream>>>(Opart, MLg, attnW);
    epi_kernel<<<dim3(NN / 64, BB), 256, 0, stream>>>(attnW, w4, b4, x, out);
}